// Round 2
// baseline (14453.363 us; speedup 1.0000x reference)
//
#include <hip/hip_runtime.h>
#include <cstdint>

#define NROWS 131072
#define HD    128      // H == IN == 128
#define NDIM  512      // 4*H
#define OUTQ  16777216 // NROWS*HD

using bf16x8 = __attribute__((ext_vector_type(8))) short;
using f32x4  = __attribute__((ext_vector_type(4))) float;

__device__ __forceinline__ uint32_t bf16rne(float f) {
  uint32_t u = __builtin_bit_cast(uint32_t, f);
  return (u + 0x7fffu + ((u >> 16) & 1u)) >> 16;
}

__device__ __forceinline__ float tanhf_fast(float v) {
  float a = __builtin_fabsf(v);
  float e = __expf(-2.0f * a);
  float t = (1.0f - e) * __builtin_amdgcn_rcpf(1.0f + e);
  return v < 0.0f ? -t : t;
}

// Pack Wf[k][n] = W[k][n] + (k>=128 ? r[k-128][n] : 0) as bf16 fragments.
// Frag (ntile*8 + kstep)*64 + lane, 8 bf16: element j =
//   Wf[kstep*32 + (lane>>4)*8 + j][ntile*16 + (lane&15)].
// This layout serves as the MFMA *A*-operand of Wf^T (rows = gate cols).
__global__ __launch_bounds__(256) void pack_weights(
    const float* __restrict__ W, const float* __restrict__ r,
    uint16_t* __restrict__ Bp) {
  int idx = blockIdx.x * 256 + threadIdx.x;   // 16384 frags total
  int l  = idx & 63;
  int ts = idx >> 6;
  int s  = ts & 7;
  int t  = ts >> 3;
  int ncol  = t * 16 + (l & 15);
  int kbase = s * 32 + ((l >> 4) << 3);
  uint32_t w[4];
#pragma unroll
  for (int jj = 0; jj < 4; ++jj) {
    int k0 = kbase + 2 * jj;
    float v0 = W[k0 * NDIM + ncol];
    float v1 = W[(k0 + 1) * NDIM + ncol];
    if (k0 >= 128)     v0 += r[(k0 - 128) * NDIM + ncol];
    if (k0 + 1 >= 128) v1 += r[(k0 + 1 - 128) * NDIM + ncol];
    w[jj] = bf16rne(v0) | (bf16rne(v1) << 16);
  }
  reinterpret_cast<uint4*>(Bp)[idx] = make_uint4(w[0], w[1], w[2], w[3]);
}

__global__ __launch_bounds__(256, 3) void slstm_fused(
    const float* __restrict__ x,  const float* __restrict__ h,
    const float* __restrict__ cs, const float* __restrict__ ns,
    const float* __restrict__ ms, const float* __restrict__ bias,
    const uint16_t* __restrict__ Bp, float* __restrict__ out) {
  __shared__ __align__(16) char smem[64 * 512];
  const int tid  = threadIdx.x;
  const int wave = tid >> 6;
  const int lane = tid & 63;
  const int row0 = blockIdx.x * 64;
  const int l15  = lane & 15;
  const int lg   = lane >> 4;

  // This lane's batch row and gate-col sub-offset (transposed D layout:
  // D[gatecol = 16*tt + 4*lg + r][batchrow = l15]).
  const int    myrow = row0 + wave * 16 + l15;
  const size_t rbase = (size_t)myrow * HD;
  const int    jb    = lg * 4;

  // ---- issue c/n/m prefetch for tiles 0 and 1 BEFORE staging (HBM latency
  //      hides behind the whole staging + GEMM prologue) ----
  f32x4 cb[3], nb[3], mb[3];
  cb[0] = *reinterpret_cast<const f32x4*>(cs + rbase + jb);
  nb[0] = *reinterpret_cast<const f32x4*>(ns + rbase + jb);
  mb[0] = *reinterpret_cast<const f32x4*>(ms + rbase + jb);
  cb[1] = *reinterpret_cast<const f32x4*>(cs + rbase + jb + 16);
  nb[1] = *reinterpret_cast<const f32x4*>(ns + rbase + jb + 16);
  mb[1] = *reinterpret_cast<const f32x4*>(ms + rbase + jb + 16);

  // ---- stage x (cols 0..127) then h (cols 128..255) as bf16, XOR-swizzled ----
#pragma unroll
  for (int i = 0; i < 8; ++i) {
    int e   = (i * 256 + tid) * 4;
    int rw  = e >> 7;
    int col = e & 127;
    float4 v = *reinterpret_cast<const float4*>(x + (size_t)(row0 + rw) * HD + col);
    uint32_t lo = bf16rne(v.x) | (bf16rne(v.y) << 16);
    uint32_t hi = bf16rne(v.z) | (bf16rne(v.w) << 16);
    int off = (rw * 512 + col * 2) ^ ((rw & 7) << 4);
    *reinterpret_cast<uint2*>(smem + off) = make_uint2(lo, hi);
  }
#pragma unroll
  for (int i = 0; i < 8; ++i) {
    int e   = (i * 256 + tid) * 4;
    int rw  = e >> 7;
    int col = e & 127;
    float4 v = *reinterpret_cast<const float4*>(h + (size_t)(row0 + rw) * HD + col);
    uint32_t lo = bf16rne(v.x) | (bf16rne(v.y) << 16);
    uint32_t hi = bf16rne(v.z) | (bf16rne(v.w) << 16);
    int off = (rw * 512 + 256 + col * 2) ^ ((rw & 7) << 4);
    *reinterpret_cast<uint2*>(smem + off) = make_uint2(lo, hi);
  }
  __syncthreads();

  // ---- x|h fragments (MFMA B-operand: B[k][batchcol]); same bytes as before ----
  bf16x8 a[8];
  {
    int rw   = wave * 16 + l15;
    int base = rw * 512 + (lg << 4);
    int swz  = (rw & 7) << 4;
#pragma unroll
    for (int s = 0; s < 8; ++s)
      a[s] = *reinterpret_cast<const bf16x8*>(smem + ((base + s * 64) ^ swz));
  }

  const bf16x8* __restrict__ Bf = reinterpret_cast<const bf16x8*>(Bp);

  // Weight double-buffer: prologue load step 0 (tt=0, s=0), gates 0..3.
  bf16x8 wb[2][4];
#pragma unroll
  for (int g = 0; g < 4; ++g)
    wb[0][g] = Bf[(size_t)((g * 8 + 0) * 8 + 0) * 64 + lane];

  f32x4 accI = {0,0,0,0}, accF = {0,0,0,0}, accZ = {0,0,0,0}, accO = {0,0,0,0};
  f32x4 bI = {0,0,0,0}, bF = {0,0,0,0}, bZ = {0,0,0,0}, bO = {0,0,0,0};

  // ---- flattened 64-step main loop: step = tt*8 + s ----
#pragma unroll
  for (int step = 0; step < 64; ++step) {
    const int tt  = step >> 3;
    const int s   = step & 7;
    const int cur = step & 1;
    const int nxt = cur ^ 1;

    if (s == 0) {
      accI = (f32x4){0,0,0,0};
      accF = (f32x4){0,0,0,0};
      accZ = (f32x4){0,0,0,0};
      accO = (f32x4){0,0,0,0};
      const int j0 = jb + 16 * tt;
      bI = *reinterpret_cast<const f32x4*>(bias + j0);
      bF = *reinterpret_cast<const f32x4*>(bias + 128 + j0);
      bZ = *reinterpret_cast<const f32x4*>(bias + 256 + j0);
      bO = *reinterpret_cast<const f32x4*>(bias + 384 + j0);
      if (tt + 2 < 8) {
        const int slot = (tt + 2) % 3;
        const size_t p = rbase + jb + 16 * (tt + 2);
        cb[slot] = *reinterpret_cast<const f32x4*>(cs + p);
        nb[slot] = *reinterpret_cast<const f32x4*>(ns + p);
        mb[slot] = *reinterpret_cast<const f32x4*>(ms + p);
      }
    }

    // issue next step's weight fragments before this step's MFMAs
    if (step < 63) {
      const int nstep = step + 1;
      const int ntt = nstep >> 3;
      const int nss = nstep & 7;
#pragma unroll
      for (int g = 0; g < 4; ++g)
        wb[nxt][g] = Bf[(size_t)((g * 8 + ntt) * 8 + nss) * 64 + lane];
    }

    accI = __builtin_amdgcn_mfma_f32_16x16x32_bf16(wb[cur][0], a[s], accI, 0, 0, 0);
    accF = __builtin_amdgcn_mfma_f32_16x16x32_bf16(wb[cur][1], a[s], accF, 0, 0, 0);
    accZ = __builtin_amdgcn_mfma_f32_16x16x32_bf16(wb[cur][2], a[s], accZ, 0, 0, 0);
    accO = __builtin_amdgcn_mfma_f32_16x16x32_bf16(wb[cur][3], a[s], accO, 0, 0, 0);

    if (s == 7) {
      const int slot = tt % 3;
      const f32x4 cv = cb[slot], nv = nb[slot], mv = mb[slot];
      f32x4 hn, cn, nn, mn;
#pragma unroll
      for (int r = 0; r < 4; ++r) {
        float i_raw = accI[r] + bI[r];
        float f_raw = accF[r] + bF[r];
        float z_raw = accZ[r] + bZ[r];
        float o_raw = accO[r] + bO[r];
        float ef  = __expf(-f_raw);
        float den = 1.0f + ef;
        float fg  = __builtin_amdgcn_rcpf(den);   // sigmoid(f_raw)
        float lgf = -__logf(den);                 // log sigmoid(f_raw)
        float mnv = fmaxf(lgf + mv[r], i_raw);    // m_new
        float ip  = __expf(i_raw - mnv);          // i'
        float zt  = tanhf_fast(z_raw);
        float og  = __builtin_amdgcn_rcpf(1.0f + __expf(-o_raw));
        float cnv = fg * cv[r] + ip * zt;         // c_new
        float nnv = fg * nv[r] + ip;              // n_new
        hn[r] = og * tanhf_fast(cnv * __builtin_amdgcn_rcpf(nnv));
        cn[r] = cnv;
        nn[r] = nnv;
        mn[r] = mnv;
      }
      const size_t p = rbase + jb + 16 * tt;
      *reinterpret_cast<f32x4*>(out + p)            = hn;
      *reinterpret_cast<f32x4*>(out + OUTQ + p)     = cn;
      *reinterpret_cast<f32x4*>(out + 2 * OUTQ + p) = nn;
      *reinterpret_cast<f32x4*>(out + 3 * OUTQ + p) = mn;
    }
  }
}

extern "C" void kernel_launch(void* const* d_in, const int* in_sizes, int n_in,
                              void* d_out, int out_size, void* d_ws, size_t ws_size,
                              hipStream_t stream) {
  const float* x = (const float*)d_in[0];
  const float* h = (const float*)d_in[1];
  const float* c = (const float*)d_in[2];
  const float* n = (const float*)d_in[3];
  const float* m = (const float*)d_in[4];
  const float* W = (const float*)d_in[5];
  const float* r = (const float*)d_in[6];
  const float* b = (const float*)d_in[7];
  uint16_t* Bp = (uint16_t*)d_ws;   // 256 KB packed bf16 weights

  pack_weights<<<64, 256, 0, stream>>>(W, r, Bp);
  slstm_fused<<<NROWS / 64, 256, 0, stream>>>(x, h, c, n, m, b, Bp, (float*)d_out);
}

// Round 3
// 227.203 us; speedup vs baseline: 63.6142x; 63.6142x over previous
//
#include <hip/hip_runtime.h>
#include <cstdint>

#define NROWS 131072
#define HD    128      // H == IN == 128
#define NDIM  512      // 4*H
#define OUTQ  16777216 // NROWS*HD

using bf16x8 = __attribute__((ext_vector_type(8))) short;
using f32x4  = __attribute__((ext_vector_type(4))) float;

__device__ __forceinline__ uint32_t bf16rne(float f) {
  uint32_t u = __builtin_bit_cast(uint32_t, f);
  return (u + 0x7fffu + ((u >> 16) & 1u)) >> 16;
}

__device__ __forceinline__ float tanhf_fast(float v) {
  float a = __builtin_fabsf(v);
  float e = __expf(-2.0f * a);
  float t = (1.0f - e) * __builtin_amdgcn_rcpf(1.0f + e);
  return v < 0.0f ? -t : t;
}

__device__ __forceinline__ f32x4 ldv(const float* p) {
  return *reinterpret_cast<const f32x4*>(p);
}

// Pack Wf[k][n] = W[k][n] + (k>=128 ? r[k-128][n] : 0) as bf16 fragments.
// Frag (ntile*8 + kstep)*64 + lane, 8 bf16: element j =
//   Wf[kstep*32 + (lane>>4)*8 + j][ntile*16 + (lane&15)].
// Serves as the MFMA A-operand of Wf^T (rows = gate cols).
__global__ __launch_bounds__(256) void pack_weights(
    const float* __restrict__ W, const float* __restrict__ r,
    uint16_t* __restrict__ Bp) {
  int idx = blockIdx.x * 256 + threadIdx.x;   // 16384 frags total
  int l  = idx & 63;
  int ts = idx >> 6;
  int s  = ts & 7;
  int t  = ts >> 3;
  int ncol  = t * 16 + (l & 15);
  int kbase = s * 32 + ((l >> 4) << 3);
  uint32_t w[4];
#pragma unroll
  for (int jj = 0; jj < 4; ++jj) {
    int k0 = kbase + 2 * jj;
    float v0 = W[k0 * NDIM + ncol];
    float v1 = W[(k0 + 1) * NDIM + ncol];
    if (k0 >= 128)     v0 += r[(k0 - 128) * NDIM + ncol];
    if (k0 + 1 >= 128) v1 += r[(k0 + 1 - 128) * NDIM + ncol];
    w[jj] = bf16rne(v0) | (bf16rne(v1) << 16);
  }
  reinterpret_cast<uint4*>(Bp)[idx] = make_uint4(w[0], w[1], w[2], w[3]);
}

__global__ __launch_bounds__(256, 3) void slstm_fused(
    const float* __restrict__ x,  const float* __restrict__ h,
    const float* __restrict__ cs, const float* __restrict__ ns,
    const float* __restrict__ ms, const float* __restrict__ bias,
    const uint16_t* __restrict__ Bp, float* __restrict__ out) {
  __shared__ __align__(16) char smem[64 * 512];
  const int tid  = threadIdx.x;
  const int wave = tid >> 6;
  const int lane = tid & 63;
  const int row0 = blockIdx.x * 64;
  const int l15  = lane & 15;
  const int lg   = lane >> 4;

  // Transposed D layout: this lane owns batchrow = wave*16 + l15 and
  // gate-cols 16*t + 4*lg + r (r=0..3) -> all epilogue I/O is f32x4.
  const int    myrow = row0 + wave * 16 + l15;
  const size_t rbase = (size_t)myrow * HD;
  const int    jb    = lg * 4;

  // ---- 2-deep c/n/m pipeline, SSA scalars only (no arrays) ----
  f32x4 cvA = ldv(cs + rbase + jb);
  f32x4 nvA = ldv(ns + rbase + jb);
  f32x4 mvA = ldv(ms + rbase + jb);
  f32x4 cvB = ldv(cs + rbase + jb + 16);
  f32x4 nvB = ldv(ns + rbase + jb + 16);
  f32x4 mvB = ldv(ms + rbase + jb + 16);

  // ---- stage x (cols 0..127) then h (cols 128..255) as bf16, XOR-swizzled ----
#pragma unroll
  for (int i = 0; i < 8; ++i) {
    int e   = (i * 256 + tid) * 4;
    int rw  = e >> 7;
    int col = e & 127;
    float4 v = *reinterpret_cast<const float4*>(x + (size_t)(row0 + rw) * HD + col);
    uint32_t lo = bf16rne(v.x) | (bf16rne(v.y) << 16);
    uint32_t hi = bf16rne(v.z) | (bf16rne(v.w) << 16);
    int off = (rw * 512 + col * 2) ^ ((rw & 7) << 4);
    *reinterpret_cast<uint2*>(smem + off) = make_uint2(lo, hi);
  }
#pragma unroll
  for (int i = 0; i < 8; ++i) {
    int e   = (i * 256 + tid) * 4;
    int rw  = e >> 7;
    int col = e & 127;
    float4 v = *reinterpret_cast<const float4*>(h + (size_t)(row0 + rw) * HD + col);
    uint32_t lo = bf16rne(v.x) | (bf16rne(v.y) << 16);
    uint32_t hi = bf16rne(v.z) | (bf16rne(v.w) << 16);
    int off = (rw * 512 + 256 + col * 2) ^ ((rw & 7) << 4);
    *reinterpret_cast<uint2*>(smem + off) = make_uint2(lo, hi);
  }
  __syncthreads();

  // ---- x|h fragments (MFMA B-operand: B[k][batchrow]) ----
  bf16x8 a[8];
  {
    int rw   = wave * 16 + l15;
    int base = rw * 512 + (lg << 4);
    int swz  = (rw & 7) << 4;
#pragma unroll
    for (int s = 0; s < 8; ++s)
      a[s] = *reinterpret_cast<const bf16x8*>(smem + ((base + s * 64) ^ swz));
  }

  const bf16x8* __restrict__ Bf = reinterpret_cast<const bf16x8*>(Bp);

  // ---- 8 column tiles, fully unrolled; all indices compile-time ----
#pragma unroll
  for (int t = 0; t < 8; ++t) {
    const f32x4 cv = cvA, nv = nvA, mv = mvA;
    cvA = cvB; nvA = nvB; mvA = mvB;
    if (t < 6) {
      const size_t pp = rbase + jb + 16 * (t + 2);
      cvB = ldv(cs + pp);
      nvB = ldv(ns + pp);
      mvB = ldv(ms + pp);
    }
    const int j0 = jb + 16 * t;
    const f32x4 bI = ldv(bias + j0);
    const f32x4 bF = ldv(bias + 128 + j0);
    const f32x4 bZ = ldv(bias + 256 + j0);
    const f32x4 bO = ldv(bias + 384 + j0);

    f32x4 accI = {0.f, 0.f, 0.f, 0.f};
    f32x4 accF = {0.f, 0.f, 0.f, 0.f};
    f32x4 accZ = {0.f, 0.f, 0.f, 0.f};
    f32x4 accO = {0.f, 0.f, 0.f, 0.f};
#pragma unroll
    for (int s = 0; s < 8; ++s) {
      accI = __builtin_amdgcn_mfma_f32_16x16x32_bf16(Bf[(size_t)(((0 * 8 + t) * 8) + s) * 64 + lane], a[s], accI, 0, 0, 0);
      accF = __builtin_amdgcn_mfma_f32_16x16x32_bf16(Bf[(size_t)(((1 * 8 + t) * 8) + s) * 64 + lane], a[s], accF, 0, 0, 0);
      accZ = __builtin_amdgcn_mfma_f32_16x16x32_bf16(Bf[(size_t)(((2 * 8 + t) * 8) + s) * 64 + lane], a[s], accZ, 0, 0, 0);
      accO = __builtin_amdgcn_mfma_f32_16x16x32_bf16(Bf[(size_t)(((3 * 8 + t) * 8) + s) * 64 + lane], a[s], accO, 0, 0, 0);
    }

    f32x4 hn, cn, nn, mn;
#pragma unroll
    for (int r = 0; r < 4; ++r) {
      float i_raw = accI[r] + bI[r];
      float f_raw = accF[r] + bF[r];
      float z_raw = accZ[r] + bZ[r];
      float o_raw = accO[r] + bO[r];
      float ef  = __expf(-f_raw);
      float den = 1.0f + ef;
      float fg  = __builtin_amdgcn_rcpf(den);   // sigmoid(f_raw)
      float lgf = -__logf(den);                 // log sigmoid(f_raw)
      float mnv = fmaxf(lgf + mv[r], i_raw);    // m_new
      float ip  = __expf(i_raw - mnv);          // i'
      float zt  = tanhf_fast(z_raw);
      float og  = __builtin_amdgcn_rcpf(1.0f + __expf(-o_raw));
      float cnv = fg * cv[r] + ip * zt;         // c_new (f' == f per source)
      float nnv = fg * nv[r] + ip;              // n_new
      hn[r] = og * tanhf_fast(cnv * __builtin_amdgcn_rcpf(nnv));
      cn[r] = cnv;
      nn[r] = nnv;
      mn[r] = mnv;
    }
    const size_t p = rbase + jb + 16 * t;
    *reinterpret_cast<f32x4*>(out + p)            = hn;
    *reinterpret_cast<f32x4*>(out + OUTQ + p)     = cn;
    *reinterpret_cast<f32x4*>(out + 2 * OUTQ + p) = nn;
    *reinterpret_cast<f32x4*>(out + 3 * OUTQ + p) = mn;
  }
}

extern "C" void kernel_launch(void* const* d_in, const int* in_sizes, int n_in,
                              void* d_out, int out_size, void* d_ws, size_t ws_size,
                              hipStream_t stream) {
  const float* x = (const float*)d_in[0];
  const float* h = (const float*)d_in[1];
  const float* c = (const float*)d_in[2];
  const float* n = (const float*)d_in[3];
  const float* m = (const float*)d_in[4];
  const float* W = (const float*)d_in[5];
  const float* r = (const float*)d_in[6];
  const float* b = (const float*)d_in[7];
  uint16_t* Bp = (uint16_t*)d_ws;   // 256 KB packed bf16 weights

  pack_weights<<<64, 256, 0, stream>>>(W, r, Bp);
  slstm_fused<<<NROWS / 64, 256, 0, stream>>>(x, h, c, n, m, b, Bp, (float*)d_out);
}

// Round 4
// 178.051 us; speedup vs baseline: 81.1753x; 1.2761x over previous
//
#include <hip/hip_runtime.h>
#include <cstdint>

#define NROWS 131072
#define HD    128      // H == IN == 128
#define NDIM  512      // 4*H
#define OUTQ  16777216 // NROWS*HD

using bf16x8 = __attribute__((ext_vector_type(8))) short;
using f32x4  = __attribute__((ext_vector_type(4))) float;

__device__ __forceinline__ uint32_t bf16rne(float f) {
  uint32_t u = __builtin_bit_cast(uint32_t, f);
  return (u + 0x7fffu + ((u >> 16) & 1u)) >> 16;
}

__device__ __forceinline__ float tanhf_fast(float v) {
  float a = __builtin_fabsf(v);
  float e = __expf(-2.0f * a);
  float t = (1.0f - e) * __builtin_amdgcn_rcpf(1.0f + e);
  return v < 0.0f ? -t : t;
}

__device__ __forceinline__ f32x4 ldv(const float* p) {
  return *reinterpret_cast<const f32x4*>(p);
}

// Async global->LDS DMA, 16B per lane. LDS dest = uniform base + lane*16;
// global src is per-lane (we pass base + lane*16).
#define ASYNC16(g, l)                                                        \
  __builtin_amdgcn_global_load_lds(                                          \
      (const __attribute__((address_space(1))) void*)(g),                    \
      (__attribute__((address_space(3))) void*)(l), 16, 0, 0)

// Pack Wf[k][n] = W[k][n] + (k>=128 ? r[k-128][n] : 0) as bf16 fragments.
// Frag (g*8 + t)*8 + s (1 KB each = 64 lanes x 16B): element j of lane l =
//   Wf[s*32 + (l>>4)*8 + j][(g*128... ) t*16 + (l&15) of gate g].
// Serves as the MFMA A-operand of Wf^T (rows = gate cols).
__global__ __launch_bounds__(256) void pack_weights(
    const float* __restrict__ W, const float* __restrict__ r,
    uint16_t* __restrict__ Bp) {
  int idx = blockIdx.x * 256 + threadIdx.x;   // 16384 frags total
  int l  = idx & 63;
  int ts = idx >> 6;
  int s  = ts & 7;
  int t  = ts >> 3;
  int ncol  = t * 16 + (l & 15);
  int kbase = s * 32 + ((l >> 4) << 3);
  uint32_t w[4];
#pragma unroll
  for (int jj = 0; jj < 4; ++jj) {
    int k0 = kbase + 2 * jj;
    float v0 = W[k0 * NDIM + ncol];
    float v1 = W[(k0 + 1) * NDIM + ncol];
    if (k0 >= 128)     v0 += r[(k0 - 128) * NDIM + ncol];
    if (k0 + 1 >= 128) v1 += r[(k0 + 1 - 128) * NDIM + ncol];
    w[jj] = bf16rne(v0) | (bf16rne(v1) << 16);
  }
  reinterpret_cast<uint4*>(Bp)[idx] = make_uint4(w[0], w[1], w[2], w[3]);
}

__global__ __launch_bounds__(256) void slstm_fused(
    const float* __restrict__ x,  const float* __restrict__ h,
    const float* __restrict__ cs, const float* __restrict__ ns,
    const float* __restrict__ ms, const float* __restrict__ bias,
    const uint16_t* __restrict__ Bp, float* __restrict__ out) {
  // 32 KB LDS, time-shared: phase 1 = x|h staging (64 rows x 512B, swizzled);
  // phase 2 = weight tile buffer (32 frags x 1 KB). 5 blocks/CU.
  __shared__ __align__(16) char smem[32768];
  const int tid  = threadIdx.x;
  const int wave = tid >> 6;
  const int lane = tid & 63;
  const int row0 = blockIdx.x * 64;
  const int l15  = lane & 15;
  const int lg   = lane >> 4;

  // Transposed D layout: lane owns batchrow = wave*16 + l15, gate-cols
  // 16*t + 4*lg + r (r=0..3) -> all epilogue I/O is f32x4.
  const int    myrow = row0 + wave * 16 + l15;
  const size_t rbase = (size_t)myrow * HD;
  const int    jb    = lg * 4;

  // c/n/m tile-0 prefetch: issued before staging (covers full HBM latency)
  f32x4 cvA = ldv(cs + rbase + jb);
  f32x4 nvA = ldv(ns + rbase + jb);
  f32x4 mvA = ldv(ms + rbase + jb);
  f32x4 cvB = {0,0,0,0}, nvB = {0,0,0,0}, mvB = {0,0,0,0};

  // ---- stage x (cols 0..127) then h (cols 128..255) as bf16, XOR-swizzled ----
#pragma unroll
  for (int i = 0; i < 8; ++i) {
    int e   = (i * 256 + tid) * 4;
    int rw  = e >> 7;
    int col = e & 127;
    float4 v = *reinterpret_cast<const float4*>(x + (size_t)(row0 + rw) * HD + col);
    uint32_t lo = bf16rne(v.x) | (bf16rne(v.y) << 16);
    uint32_t hi = bf16rne(v.z) | (bf16rne(v.w) << 16);
    int off = (rw * 512 + col * 2) ^ ((rw & 7) << 4);
    *reinterpret_cast<uint2*>(smem + off) = make_uint2(lo, hi);
  }
#pragma unroll
  for (int i = 0; i < 8; ++i) {
    int e   = (i * 256 + tid) * 4;
    int rw  = e >> 7;
    int col = e & 127;
    float4 v = *reinterpret_cast<const float4*>(h + (size_t)(row0 + rw) * HD + col);
    uint32_t lo = bf16rne(v.x) | (bf16rne(v.y) << 16);
    uint32_t hi = bf16rne(v.z) | (bf16rne(v.w) << 16);
    int off = (rw * 512 + 256 + col * 2) ^ ((rw & 7) << 4);
    *reinterpret_cast<uint2*>(smem + off) = make_uint2(lo, hi);
  }
  __syncthreads();

  // ---- x|h fragments (MFMA B-operand: B[k][batchrow]) ----
  bf16x8 a[8];
  {
    int rw   = wave * 16 + l15;
    int base = rw * 512 + (lg << 4);
    int swz  = (rw & 7) << 4;
#pragma unroll
    for (int s = 0; s < 8; ++s)
      a[s] = *reinterpret_cast<const bf16x8*>(smem + ((base + s * 64) ^ swz));
  }
  __syncthreads();   // region handoff: staging area becomes weight buffer

  const char* wBytes = (const char*)Bp;
  // DMA tile 0: wave w stages gate g=w, k-steps 0..7 (8 x 1KB frags)
  {
    const char* gsrc = wBytes + (((size_t)(wave * 8 + 0) * 8) << 10) + (lane << 4);
    char* ldst = smem + (wave << 13);
#pragma unroll
    for (int k = 0; k < 8; ++k)
      ASYNC16(gsrc + (k << 10), ldst + (k << 10));
  }

  // ---- 8 column tiles, fully unrolled ----
#pragma unroll
  for (int t = 0; t < 8; ++t) {
    __syncthreads();   // barrier A: compiler drains vmcnt -> tile t weights ready

    // c/n/m prefetch for t+1: a full tile (~MFMA+epilogue) of cover
    if (t < 7) {
      const size_t pp = rbase + jb + 16 * (t + 1);
      cvB = ldv(cs + pp);
      nvB = ldv(ns + pp);
      mvB = ldv(ms + pp);
    }
    const int j0 = jb + 16 * t;
    const f32x4 bI = ldv(bias + j0);
    const f32x4 bF = ldv(bias + 128 + j0);
    const f32x4 bZ = ldv(bias + 256 + j0);
    const f32x4 bO = ldv(bias + 384 + j0);

    f32x4 accI = {0.f, 0.f, 0.f, 0.f};
    f32x4 accF = {0.f, 0.f, 0.f, 0.f};
    f32x4 accZ = {0.f, 0.f, 0.f, 0.f};
    f32x4 accO = {0.f, 0.f, 0.f, 0.f};
#pragma unroll
    for (int s = 0; s < 8; ++s) {
      const int lo = lane << 4;
      bf16x8 wI = *reinterpret_cast<const bf16x8*>(smem + ((0 * 8 + s) << 10) + lo);
      bf16x8 wF = *reinterpret_cast<const bf16x8*>(smem + ((1 * 8 + s) << 10) + lo);
      bf16x8 wZ = *reinterpret_cast<const bf16x8*>(smem + ((2 * 8 + s) << 10) + lo);
      bf16x8 wO = *reinterpret_cast<const bf16x8*>(smem + ((3 * 8 + s) << 10) + lo);
      accI = __builtin_amdgcn_mfma_f32_16x16x32_bf16(wI, a[s], accI, 0, 0, 0);
      accF = __builtin_amdgcn_mfma_f32_16x16x32_bf16(wF, a[s], accF, 0, 0, 0);
      accZ = __builtin_amdgcn_mfma_f32_16x16x32_bf16(wZ, a[s], accZ, 0, 0, 0);
      accO = __builtin_amdgcn_mfma_f32_16x16x32_bf16(wO, a[s], accO, 0, 0, 0);
    }
    __syncthreads();   // barrier B: all waves done reading tile t weights

    // DMA tile t+1 now; its latency hides under the epilogue below
    if (t < 7) {
      const char* gsrc = wBytes + (((size_t)(wave * 8 + (t + 1)) * 8) << 10) + (lane << 4);
      char* ldst = smem + (wave << 13);
#pragma unroll
      for (int k = 0; k < 8; ++k)
        ASYNC16(gsrc + (k << 10), ldst + (k << 10));
    }

    f32x4 hn, cn, nn, mn;
#pragma unroll
    for (int rr = 0; rr < 4; ++rr) {
      float i_raw = accI[rr] + bI[rr];
      float f_raw = accF[rr] + bF[rr];
      float z_raw = accZ[rr] + bZ[rr];
      float o_raw = accO[rr] + bO[rr];
      float ef  = __expf(-f_raw);
      float den = 1.0f + ef;
      float fg  = __builtin_amdgcn_rcpf(den);   // sigmoid(f_raw)
      float lgf = -__logf(den);                 // log sigmoid(f_raw)
      float mnv = fmaxf(lgf + mvA[rr], i_raw);  // m_new
      float ip  = __expf(i_raw - mnv);          // i'
      float zt  = tanhf_fast(z_raw);
      float og  = __builtin_amdgcn_rcpf(1.0f + __expf(-o_raw));
      float cnv = fg * cvA[rr] + ip * zt;       // c_new (f' == f per source)
      float nnv = fg * nvA[rr] + ip;            // n_new
      hn[rr] = og * tanhf_fast(cnv * __builtin_amdgcn_rcpf(nnv));
      cn[rr] = cnv;
      nn[rr] = nnv;
      mn[rr] = mnv;
    }
    const size_t p = rbase + jb + 16 * t;
    *reinterpret_cast<f32x4*>(out + p)            = hn;
    *reinterpret_cast<f32x4*>(out + OUTQ + p)     = cn;
    *reinterpret_cast<f32x4*>(out + 2 * OUTQ + p) = nn;
    *reinterpret_cast<f32x4*>(out + 3 * OUTQ + p) = mn;

    cvA = cvB; nvA = nvB; mvA = mvB;
  }
}

extern "C" void kernel_launch(void* const* d_in, const int* in_sizes, int n_in,
                              void* d_out, int out_size, void* d_ws, size_t ws_size,
                              hipStream_t stream) {
  const float* x = (const float*)d_in[0];
  const float* h = (const float*)d_in[1];
  const float* c = (const float*)d_in[2];
  const float* n = (const float*)d_in[3];
  const float* m = (const float*)d_in[4];
  const float* W = (const float*)d_in[5];
  const float* r = (const float*)d_in[6];
  const float* b = (const float*)d_in[7];
  uint16_t* Bp = (uint16_t*)d_ws;   // 256 KB packed bf16 weights

  pack_weights<<<64, 256, 0, stream>>>(W, r, Bp);
  slstm_fused<<<NROWS / 64, 256, 0, stream>>>(x, h, c, n, m, b, Bp, (float*)d_out);
}